// Round 6
// baseline (420.793 us; speedup 1.0000x reference)
//
#include <hip/hip_runtime.h>

#define KK 64
#define TT 1024
#define BB 256
#define NG 16          // batch groups (waves)
#define GB 16          // batches per group

typedef float  f32x4  __attribute__((ext_vector_type(4)));
typedef float  f32x2  __attribute__((ext_vector_type(2)));
typedef short  bf16x8 __attribute__((ext_vector_type(8)));

// pack two fp32 -> packed bf16 pair (round-half-up via +0x8000, then take high16)
__device__ __forceinline__ unsigned bf16pair(float lo, float hi) {
    unsigned l = __float_as_uint(lo) + 0x8000u;
    unsigned h = __float_as_uint(hi) + 0x8000u;
    // result bytes [l.b2, l.b3, h.b2, h.b3]  (low16 = bf16(lo))
    return __builtin_amdgcn_perm(h, l, 0x07060302u);
}

// ---------------------------------------------------------------------------
// Pre-pass: E[b][t][m] = exp(feats[b][t][m]) as fp8 e4m3, packed so that the
// recurrent wave's lane L reads ALL 16 of its values with one dwordx4 load.
// Lane mapping (matches MFMA C/D layout): n = L&15 (batch in group),
// quad = L>>4; dword d holds states m = 16d + 4*quad + {0..3}.
// exp(feats) <= e^~5.7 ~ 300 < 448 = fp8 max (saturating cvt), no inf/nan.
// ---------------------------------------------------------------------------
__global__ __launch_bounds__(64) void crf_prepass(
    const float* __restrict__ feats, uint4* __restrict__ wsE)
{
    const int bid  = blockIdx.x;           // g*1024 + t
    const int g    = bid >> 10, t = bid & 1023;
    const int L    = threadIdx.x, nL = L & 15, quad = L >> 4;
    const int b    = g * GB + nL;
    const float* fp = feats + ((size_t)b * TT + t) * KK + 4 * quad;
    unsigned dw[4];
    #pragma unroll
    for (int d = 0; d < 4; ++d) {
        float4 x = *(const float4*)(fp + 16 * d);
        int w = 0;
        w = __builtin_amdgcn_cvt_pk_fp8_f32(__expf(x.x), __expf(x.y), w, false);
        w = __builtin_amdgcn_cvt_pk_fp8_f32(__expf(x.z), __expf(x.w), w, true);
        dw[d] = (unsigned)w;
    }
    wsE[(size_t)bid * 64 + L] = make_uint4(dw[0], dw[1], dw[2], dw[3]);
}

// ---------------------------------------------------------------------------
// Recurrent forward: one wave per 16 batches. Probability domain:
//   alpha_{t}[m][n] = (sum_k ET[m][k] * alpha_{t-1}[k][n]) * E_t[m][n]
// as 8x mfma_f32_16x16x32_bf16 (4 M-tiles x 2 K-chunks), ET constant in
// A-frags. D->B relayout each step via a 2.3KB LDS round-trip (single wave,
// DS ops in-order => no barrier). Per-column renorm every 4 steps.
// Verified layouts: A[m=lane&15][k=quad*8+j], D: col=lane&15,row=quad*4+reg.
// Assumed: B[k=quad*8+j][n=lane&15] (symmetric to A).
// ---------------------------------------------------------------------------
__global__ __launch_bounds__(64)
__attribute__((amdgpu_waves_per_eu(1, 1)))
void crf_forward(const uint4* __restrict__ wsE,
                 const float* __restrict__ trans,
                 const float* __restrict__ masks,
                 float* __restrict__ out)
{
    const int g  = blockIdx.x;
    const int L  = threadIdx.x, nL = L & 15, quad = L >> 4;
    __shared__ __align__(16) unsigned short smem[16 * 72];  // [n][m], stride 72 bf16

    // A-fragments: bf16(exp(trans[m][k])), m = 16*mt + nL, k = 32*kc + 8*quad + j
    bf16x8 afr[4][2];
    #pragma unroll
    for (int mt = 0; mt < 4; ++mt)
        #pragma unroll
        for (int kc = 0; kc < 2; ++kc) {
            const float* tp = trans + (16 * mt + nL) * KK + 32 * kc + 8 * quad;
            float4 x = *(const float4*)tp;
            float4 y = *(const float4*)(tp + 4);
            uint4 u = make_uint4(
                bf16pair(__expf(x.x), __expf(x.y)),
                bf16pair(__expf(x.z), __expf(x.w)),
                bf16pair(__expf(y.x), __expf(y.y)),
                bf16pair(__expf(y.z), __expf(y.w)));
            afr[mt][kc] = *(bf16x8*)&u;
        }

    // alpha in D-layout: aD[4*mt+r] = alpha[m = 16*mt + 4*quad + r][n = nL]
    float aD[16];
    #pragma unroll
    for (int k = 0; k < 16; ++k) aD[k] = 0.f;
    if (quad == 0) aD[0] = 1.f;          // alpha0 = delta(START=0), every column
    float offset = 0.f;                   // per-column log-scale (quad-replicated)

    const float* mb = masks + (size_t)(g * GB + nL) * TT;
    const uint4* eb = wsE + (size_t)(g << 10) * 64;

    char*       wp = (char*)smem + (nL * 72 + 4 * quad) * 2;        // writes
    const char* rp = (const char*)smem + (nL * 72 + 8 * quad) * 2;  // reads

    uint4 er[4]; float mr[4];
    #pragma unroll
    for (int u = 0; u < 4; ++u) {
        er[u] = eb[(size_t)(1 + u) * 64 + L];
        mr[u] = mb[1 + u];
    }

    for (int t0 = 1; t0 < TT; t0 += 4) {
        // prefetch next group (HBM latency hidden behind ~4 steps of work)
        uint4 pe[4]; float pm[4];
        #pragma unroll
        for (int u = 0; u < 4; ++u) {
            int tn = t0 + 4 + u; tn = tn < TT ? tn : TT - 1;
            pe[u] = eb[(size_t)tn * 64 + L];
            pm[u] = mb[tn];
        }
        #pragma unroll
        for (int u = 0; u < 4; ++u) {
            float mk = (t0 + u < TT) ? mr[u] : 0.f;   // t=1024 (last group) masked

            // stage B = bf16(aD): write [n][m], read B[k][n] rows
            #pragma unroll
            for (int mt = 0; mt < 4; ++mt) {
                unsigned p0 = bf16pair(aD[4*mt+0], aD[4*mt+1]);
                unsigned p1 = bf16pair(aD[4*mt+2], aD[4*mt+3]);
                *(uint2*)(wp + 32 * mt) = make_uint2(p0, p1);
            }
            bf16x8 b0 = *(const bf16x8*)rp;           // k = 8*quad + j
            bf16x8 b1 = *(const bf16x8*)(rp + 64);    // k = 32 + 8*quad + j

            f32x4 acc[4];
            #pragma unroll
            for (int mt = 0; mt < 4; ++mt) {
                f32x4 z = {0.f, 0.f, 0.f, 0.f};
                z = __builtin_amdgcn_mfma_f32_16x16x32_bf16(afr[mt][0], b0, z, 0, 0, 0);
                acc[mt] = __builtin_amdgcn_mfma_f32_16x16x32_bf16(afr[mt][1], b1, z, 0, 0, 0);
            }

            // unpack fp8 emissions (D-layout order) and blend
            float e[16];
            unsigned edw[4] = {er[u].x, er[u].y, er[u].z, er[u].w};
            #pragma unroll
            for (int d = 0; d < 4; ++d) {
                f32x2 lo = __builtin_amdgcn_cvt_pk_f32_fp8((int)edw[d], false);
                f32x2 hi = __builtin_amdgcn_cvt_pk_f32_fp8((int)edw[d], true);
                e[4*d+0] = lo.x; e[4*d+1] = lo.y; e[4*d+2] = hi.x; e[4*d+3] = hi.y;
            }
            bool up = (mk != 0.f);
            #pragma unroll
            for (int k = 0; k < 16; ++k) {
                float an = acc[k >> 2][k & 3] * e[k];
                aD[k] = up ? an : aD[k];
            }
        }

        // per-column renorm (column n lives in lanes {n, n+16, n+32, n+48})
        float c = aD[0];
        #pragma unroll
        for (int k = 1; k < 16; ++k) c = fmaxf(c, aD[k]);
        c = fmaxf(c, __shfl_xor(c, 16, 64));
        c = fmaxf(c, __shfl_xor(c, 32, 64));
        c = fmaxf(c, 1e-30f);
        float rc = __builtin_amdgcn_rcpf(c);
        #pragma unroll
        for (int k = 0; k < 16; ++k) aD[k] *= rc;
        offset += __logf(c);

        #pragma unroll
        for (int u = 0; u < 4; ++u) { er[u] = pe[u]; mr[u] = pm[u]; }
    }

    // fwd[n] = offset + log(sum_m alpha[m][n])
    float s = aD[0];
    #pragma unroll
    for (int k = 1; k < 16; ++k) s += aD[k];
    s += __shfl_xor(s, 16, 64);
    s += __shfl_xor(s, 32, 64);
    if (L < 16) {
        float fwd = offset + __logf(s);
        atomicAdd(out, fwd * (1.f / 256.f));
    }
}

// ---------------------------------------------------------------------------
// Gold score: sum_t (trans[ct,pt] + feats[b,t,ct]) * mask[b,t], one block/batch
// ---------------------------------------------------------------------------
__global__ __launch_bounds__(64) void crf_gold(
    const float* __restrict__ feats, const float* __restrict__ trans,
    const int* __restrict__ tags, const float* __restrict__ masks,
    float* __restrict__ out)
{
    const int b = blockIdx.x, L = threadIdx.x;
    const int*   tg = tags + b * TT;
    const float* fb = feats + (size_t)b * TT * KK;
    const float* mp = masks + b * TT;
    float gsum = 0.f;
    for (int t = 1 + L; t < TT; t += 64) {
        int ct = tg[t], pt = tg[t - 1];
        gsum += (trans[ct * KK + pt] + fb[t * KK + ct]) * mp[t];
    }
    #pragma unroll
    for (int off = 32; off >= 1; off >>= 1)
        gsum += __shfl_xor(gsum, off, 64);
    if (L == 0) atomicAdd(out, -gsum * (1.f / 256.f));
}

extern "C" void kernel_launch(void* const* d_in, const int* in_sizes, int n_in,
                              void* d_out, int out_size, void* d_ws, size_t ws_size,
                              hipStream_t stream) {
    const float* feats = (const float*)d_in[0];
    const float* trans = (const float*)d_in[1];
    const int*   tags  = (const int*)d_in[2];
    const float* masks = (const float*)d_in[3];
    float* out  = (float*)d_out;
    uint4* wsE  = (uint4*)d_ws;   // 16 MB: NG*TT*64 lanes * 16 B

    hipMemsetAsync(out, 0, sizeof(float), stream);
    crf_prepass<<<NG * TT, 64, 0, stream>>>(feats, wsE);
    crf_forward<<<NG, 64, 0, stream>>>(wsE, trans, masks, out);
    crf_gold<<<BB, 64, 0, stream>>>(feats, trans, tags, masks, out);
}